// Round 19
// baseline (528.605 us; speedup 1.0000x reference)
//
// MoCA fused pipeline — round 19: GEMMs switched to v_mfma_f32_32x32x16_f16
// (half the MFMA instructions, 2382-TF shape ceiling; LDS staging/rotation/waits
// identical). conv3 reverted to r13; fused slab-softmax kept. Rest = round 16.
#include <hip/hip_runtime.h>

#define Bz 8
#define Sz 2048
#define Dz 1024

typedef __attribute__((ext_vector_type(8))) _Float16 f16x8;
typedef __attribute__((ext_vector_type(8))) short short8v;
typedef __attribute__((ext_vector_type(4))) short short4v;
typedef __attribute__((ext_vector_type(16))) float f32x16;

__device__ __forceinline__ short f2h(float f) {
    _Float16 h = (_Float16)f;
    return __builtin_bit_cast(short, h);
}
__device__ __forceinline__ float h2f(short s) {
    return (float)__builtin_bit_cast(_Float16, s);
}
__device__ __forceinline__ void gld16(const void* g, void* l) {
    __builtin_amdgcn_global_load_lds(
        (const __attribute__((address_space(1))) void*)g,
        (__attribute__((address_space(3))) void*)l, 16, 0, 0);
}

// ---------------- fused 5x5 convs over x — 1 row/block (round-13 proven) ----------------
__global__ __launch_bounds__(256) void conv3_kernel(
    const float* __restrict__ x,
    const float* __restrict__ w1, const float* __restrict__ b1,
    const float* __restrict__ w2, const float* __restrict__ b2,
    short* __restrict__ x16, short* __restrict__ C1f, short* __restrict__ C2f)
{
    __shared__ float w[50];
    __shared__ float bias[2];
    const size_t SD = (size_t)Sz * Dz;
    int tid = threadIdx.x;
    if (tid < 25) w[tid] = w1[tid];
    else if (tid < 50) w[tid] = w2[tid - 25];
    if (tid == 50) { bias[0] = b1[0]; bias[1] = b2[0]; }
    __syncthreads();

    int d4 = tid * 4;
    int y = blockIdx.y;
    int s = ((y & 7) << 8) | (y >> 3);
    int b = blockIdx.z;
    const float* xb = x + (size_t)b * SD + d4;

    float wv[5][12];
#pragma unroll
    for (int i = 0; i < 5; i++) {
        int ss = s + i - 2;
        int ssc = ss < 0 ? 0 : (ss >= Sz ? Sz - 1 : ss);
        const float* rp = xb + (size_t)ssc * Dz;
        if (d4 > 0) *(float4*)&wv[i][0] = *(const float4*)(rp - 4);
        else { wv[i][0] = wv[i][1] = wv[i][2] = wv[i][3] = 0.f; }
        *(float4*)&wv[i][4] = *(const float4*)rp;
        if (d4 < 1020) *(float4*)&wv[i][8] = *(const float4*)(rp + 4);
        else { wv[i][8] = wv[i][9] = wv[i][10] = wv[i][11] = 0.f; }
        if (ss != ssc) {
#pragma unroll
            for (int q = 0; q < 12; q++) wv[i][q] = 0.f;
        }
    }

    float o1[4] = {}, o2[4] = {};
#pragma unroll
    for (int i = 0; i < 5; i++)
#pragma unroll
        for (int j = 0; j < 5; j++) {
            float c1w = w[i * 5 + j], c2w = w[25 + j * 5 + i];
#pragma unroll
            for (int q = 0; q < 4; q++) {
                float v = wv[i][q + j + 2];
                o1[q] = fmaf(c1w, v, o1[q]);
                o2[q] = fmaf(c2w, v, o2[q]);
            }
        }
    size_t o = (size_t)b * SD + (size_t)s * Dz + d4;
    short4v hx, h1, h2;
#pragma unroll
    for (int q = 0; q < 4; q++) {
        hx[q] = f2h(wv[2][q + 4]);
        h1[q] = f2h(o1[q] + bias[0]);
        h2[q] = f2h(o2[q] + bias[1]);
    }
    *(short4v*)(x16 + o) = hx;
    *(short4v*)(C1f + o) = h1;
    *(short4v*)(C2f + o) = h2;
}

// ---------------- fused conv_g (5x5) + transpose: x[s,d] -> C4T[d,s] fp16 ----------------
__global__ __launch_bounds__(256) void convT_kernel(
    const float* __restrict__ x, const float* __restrict__ w4,
    const float* __restrict__ b4, short* __restrict__ C4T)
{
    __shared__ float xs[68][73];
    __shared__ short ct[64][72];
    __shared__ float w[25];
    __shared__ float bb;
    const size_t SD = (size_t)Sz * Dz;
    int tid = threadIdx.x;
    if (tid < 25) w[tid] = w4[tid];
    if (tid == 25) bb = b4[0];

    int s0 = blockIdx.x * 64, d0 = blockIdx.y * 64, b = blockIdx.z;
    const float* xb = x + (size_t)b * SD;
    for (int k = tid; k < 68 * 68; k += 256) {
        int r = k / 68, c = k - r * 68;
        int gr = s0 - 2 + r, gc = d0 - 2 + c;
        float v = 0.f;
        if (gr >= 0 && gr < Sz && gc >= 0 && gc < Dz) v = xb[(size_t)gr * Dz + gc];
        xs[r][c] = v;
    }
    __syncthreads();

    int sl = tid & 63, dg = tid >> 6;
    float acc[16];
#pragma unroll
    for (int q = 0; q < 16; q++) acc[q] = bb;
#pragma unroll
    for (int i = 0; i < 5; i++) {
        float row[20];
#pragma unroll
        for (int m = 0; m < 20; m++) row[m] = xs[sl + i][dg * 16 + m];
#pragma unroll
        for (int j = 0; j < 5; j++) {
            float wv = w[i * 5 + j];
#pragma unroll
            for (int q = 0; q < 16; q++) acc[q] = fmaf(wv, row[q + j], acc[q]);
        }
    }
#pragma unroll
    for (int q = 0; q < 16; q++) ct[dg * 16 + q][sl] = f2h(acc[q]);
    __syncthreads();

    int dl = tid >> 2, sc = (tid & 3) * 16;
    f16x8 v0 = *(const f16x8*)&ct[dl][sc];
    f16x8 v1 = *(const f16x8*)&ct[dl][sc + 8];
    short* op = C4T + (size_t)b * SD + (size_t)(d0 + dl) * Sz + s0 + sc;
    *(f16x8*)op = v0;
    *(f16x8*)(op + 8) = v1;
}

// ---------------- 8-phase 256x256 logit GEMM, 32x32x16 MFMA, fp16 out ----------------
// z<8: G-map (x.x^T, -1024 on diag, 256-tile lower-triangle skip), z>=8: A-map.
__global__ __launch_bounds__(512, 2) void logit8_f16(
    const short* __restrict__ Ag, const short* __restrict__ Bg,
    const short* __restrict__ Aa, const short* __restrict__ Ba,
    short* __restrict__ Qg, short* __restrict__ Qa,
    int rlo, int sq256off, long PS)
{
    __shared__ char lds[131072];

    int flat = blockIdx.x + 8 * (blockIdx.y + 4 * blockIdx.z);
    int nid = (flat & 7) * 64 + (flat >> 3);
    int bx = nid & 7, by = (nid >> 3) & 3, bz = nid >> 5;
    const int map = bz >> 3, bzb = bz & 7;
    if (map == 0) {
        int ntl = bx - sq256off;
        if (ntl >= 0 && ntl < 4 && ntl < by) return;
    }

    const size_t SD = (size_t)Sz * Dz;
    const int K = Dz;
    const short* A = (map ? Aa : Ag) + (size_t)bzb * SD;
    const short* B = (map ? Ba : Bg) + (size_t)bzb * SD;
    short* Q = (map ? Qa : Qg) + (size_t)bzb * PS;

    const int m0 = by * 256, n0 = bx * 256;
    const int t = threadIdx.x;
    const int lane = t & 63;
    const int w = t >> 6;
    const int wm = w >> 2, wn = w & 3;
    const int l31 = lane & 31, l5 = lane >> 5, l7 = lane & 7;

    const int cc16 = ((t & 7) ^ ((t >> 3) & 7)) * 16;
    const int tr = t >> 3;
    const int bdst = (t >> 8) * 8192 + ((t >> 3) & 31) * 128 + (t & 7) * 16;

    auto STA = [&](int tile, int h) {
        char* base = lds + (tile & 1) * 65536;
#pragma unroll
        for (int j = 0; j < 2; j++) {
            int row = m0 + j * 128 + h * 64 + tr;
            gld16((const char*)A + ((size_t)row * K + tile * 64) * 2 + cc16,
                  base + j * 16384 + h * 8192 + t * 16);
        }
    };
    auto STB = [&](int tile, int h) {
        char* base = lds + (tile & 1) * 65536 + 32768;
#pragma unroll
        for (int j = 0; j < 2; j++) {
            int u = j * 64 + tr;
            int row = n0 + (u >> 5) * 64 + h * 32 + (u & 31);
            gld16((const char*)B + ((size_t)row * K + tile * 64) * 2 + cc16,
                  base + j * 16384 + h * 4096 + bdst);
        }
    };

    // 32x32x16 fragment reads: row = base + (lane&31), chunk = ks*2 + (lane>>5),
    // LDS is linear (row_local*128) with slot = chunk ^ (row&7), row&7 == lane&7.
    int aoff[4], boff[4];
#pragma unroll
    for (int ks = 0; ks < 4; ks++) {
        int slot = ((ks * 2 + l5) ^ l7) * 16;
        aoff[ks] = (wm * 128 + l31) * 128 + slot;
        boff[ks] = (wn * 64 + l31) * 128 + slot;
    }

    f16x8 aR[2][4];     // [frag within half][ks]
    f16x8 bR[2][4];     // [which][ks]
    f32x16 acc[4][2];
#pragma unroll
    for (int i = 0; i < 4; i++)
#pragma unroll
        for (int j = 0; j < 2; j++) acc[i][j] = (f32x16)(0.f);

    auto LDA = [&](int qa, int d) {       // A frags {2qa, 2qa+1}, all 4 ksteps
        const char* p = lds + d * 65536 + qa * 8192;
#pragma unroll
        for (int i = 0; i < 2; i++)
#pragma unroll
            for (int ks = 0; ks < 4; ks++)
                aR[i][ks] = *(const f16x8*)(p + i * 4096 + aoff[ks]);
    };
    auto LDB = [&](int qb, int d, int which) {   // B frag qb, 4 ksteps
        const char* p = lds + d * 65536 + 32768 + qb * 4096;
#pragma unroll
        for (int ks = 0; ks < 4; ks++)
            bR[which][ks] = *(const f16x8*)(p + boff[ks]);
    };
#define MMQ(qa, qb, which)                                                        \
    __builtin_amdgcn_s_setprio(1);                                                \
    _Pragma("unroll") for (int i = 0; i < 2; i++)                                 \
        _Pragma("unroll") for (int ks = 0; ks < 4; ks++)                          \
            acc[(qa)*2 + i][qb] = __builtin_amdgcn_mfma_f32_32x32x16_f16(         \
                aR[i][ks], bR[which][ks], acc[(qa)*2 + i][qb], 0, 0, 0);          \
    __builtin_amdgcn_s_setprio(0);

#define BAR()  __builtin_amdgcn_s_barrier(); __builtin_amdgcn_sched_barrier(0)
#define WAIT4() asm volatile("s_waitcnt vmcnt(4)" ::: "memory"); __builtin_amdgcn_sched_barrier(0)
#define WAIT0() asm volatile("s_waitcnt vmcnt(0)" ::: "memory"); __builtin_amdgcn_sched_barrier(0)

    STA(0, 0); STB(0, 0); STA(0, 1); STB(0, 1);
    STA(1, 0); STB(1, 0);

    const int NIT = K / 128;
    for (int it = 0; it < NIT - 1; ++it) {
        const int V = 2 * it + 1, W = 2 * it + 2, X = 2 * it + 3;
        WAIT4(); BAR();
        STA(V, 1); LDA(0, 0); LDB(0, 0, 0); MMQ(0, 0, 0);
        BAR();
        STB(V, 1); LDB(1, 0, 1); MMQ(0, 1, 1);
        BAR();
        STA(W, 0); LDA(1, 0); MMQ(1, 0, 0);
        BAR();
        STB(W, 0); MMQ(1, 1, 1);
        WAIT4(); BAR();
        STA(W, 1); LDA(0, 1); LDB(0, 1, 0); MMQ(0, 0, 0);
        BAR();
        STB(W, 1); LDB(1, 1, 1); MMQ(0, 1, 1);
        BAR();
        STA(X, 0); LDA(1, 1); MMQ(1, 0, 0);
        BAR();
        STB(X, 0); MMQ(1, 1, 1);
    }
    {
        const int V = 2 * NIT - 1;
        WAIT4(); BAR();
        STA(V, 1); LDA(0, 0); LDB(0, 0, 0); MMQ(0, 0, 0);
        BAR();
        STB(V, 1); LDB(1, 0, 1); MMQ(0, 1, 1);
        BAR();
        LDA(1, 0); MMQ(1, 0, 0);
        BAR();
        MMQ(1, 1, 1);
        WAIT0(); BAR();
        LDA(0, 1); LDB(0, 1, 0); MMQ(0, 0, 0);
        BAR();
        LDB(1, 1, 1); MMQ(0, 1, 1);
        BAR();
        LDA(1, 1); MMQ(1, 0, 0);
        BAR();
        MMQ(1, 1, 1);
    }
#undef MMQ
#undef BAR
#undef WAIT4
#undef WAIT0

    // epilogue: 32x32 C/D layout col=lane&31, row=(r&3)+8*(r>>2)+4*(lane>>5)
#pragma unroll
    for (int fa = 0; fa < 4; fa++)
#pragma unroll
        for (int fb = 0; fb < 2; fb++) {
            int col = n0 + wn * 64 + fb * 32 + l31;
#pragma unroll
            for (int r = 0; r < 16; r++) {
                int rowg = m0 + wm * 128 + fa * 32 + (r & 3) + 8 * (r >> 2) + 4 * l5;
                float o = acc[fa][fb][r];
                if (map == 0 && rlo + rowg == col) o -= 1024.f;
                Q[(size_t)rowg * Sz + col] = f2h(o);
            }
        }
}

// ---------------- 8-phase 256x256 Wz GEMM, 32x32x16 MFMA: M=2048 full ----------------
__global__ __launch_bounds__(512, 2) void wz8_f16(
    const short* __restrict__ M0, const short* __restrict__ M1,
    const short* __restrict__ C4Tm,
    const float* __restrict__ X, float* __restrict__ Out,
    long psM0, long psM1)
{
    __shared__ char lds[131072];

    int flat = blockIdx.x + 4 * (blockIdx.y + 8 * blockIdx.z);
    int nid = (flat & 7) * 32 + (flat >> 3);
    int bx = nid & 3, by = (nid >> 2) & 7, bz = nid >> 5;

    const size_t SD = (size_t)Sz * Dz;
    const int K = Sz;
    const short* A0 = M0 + (size_t)bz * psM0;
    const short* A1 = M1 + (size_t)bz * psM1;
    const short* B = C4Tm + (size_t)bz * SD;
    const float* Src = X + (size_t)bz * SD;
    float* C = Out + (size_t)bz * SD;

    const int m0 = by * 256, n0 = bx * 256;
    const int t = threadIdx.x;
    const int lane = t & 63;
    const int w = t >> 6;
    const int wm = w >> 2, wn = w & 3;
    const int l31 = lane & 31, l5 = lane >> 5, l7 = lane & 7;

    const int cc16 = ((t & 7) ^ ((t >> 3) & 7)) * 16;
    const int tr = t >> 3;
    const int bdst = (t >> 8) * 8192 + ((t >> 3) & 31) * 128 + (t & 7) * 16;

    auto STA = [&](int tile, int h) {
        char* base = lds + (tile & 1) * 65536;
#pragma unroll
        for (int j = 0; j < 2; j++) {
            int row = m0 + j * 128 + h * 64 + tr;
            const short* src = (row < 1022) ? (A0 + (size_t)row * K)
                                            : (A1 + (size_t)(row - 1022) * K);
            gld16((const char*)src + (size_t)tile * 128 + cc16,
                  base + j * 16384 + h * 8192 + t * 16);
        }
    };
    auto STB = [&](int tile, int h) {
        char* base = lds + (tile & 1) * 65536 + 32768;
#pragma unroll
        for (int j = 0; j < 2; j++) {
            int u = j * 64 + tr;
            int row = n0 + (u >> 5) * 64 + h * 32 + (u & 31);
            gld16((const char*)B + ((size_t)row * K + tile * 64) * 2 + cc16,
                  base + j * 16384 + h * 4096 + bdst);
        }
    };

    int aoff[4], boff[4];
#pragma unroll
    for (int ks = 0; ks < 4; ks++) {
        int slot = ((ks * 2 + l5) ^ l7) * 16;
        aoff[ks] = (wm * 128 + l31) * 128 + slot;
        boff[ks] = (wn * 64 + l31) * 128 + slot;
    }

    f16x8 aR[2][4];
    f16x8 bR[2][4];
    f32x16 acc[4][2];
#pragma unroll
    for (int i = 0; i < 4; i++)
#pragma unroll
        for (int j = 0; j < 2; j++) acc[i][j] = (f32x16)(0.f);

    auto LDA = [&](int qa, int d) {
        const char* p = lds + d * 65536 + qa * 8192;
#pragma unroll
        for (int i = 0; i < 2; i++)
#pragma unroll
            for (int ks = 0; ks < 4; ks++)
                aR[i][ks] = *(const f16x8*)(p + i * 4096 + aoff[ks]);
    };
    auto LDB = [&](int qb, int d, int which) {
        const char* p = lds + d * 65536 + 32768 + qb * 4096;
#pragma unroll
        for (int ks = 0; ks < 4; ks++)
            bR[which][ks] = *(const f16x8*)(p + boff[ks]);
    };
#define MMQ(qa, qb, which)                                                        \
    __builtin_amdgcn_s_setprio(1);                                                \
    _Pragma("unroll") for (int i = 0; i < 2; i++)                                 \
        _Pragma("unroll") for (int ks = 0; ks < 4; ks++)                          \
            acc[(qa)*2 + i][qb] = __builtin_amdgcn_mfma_f32_32x32x16_f16(         \
                aR[i][ks], bR[which][ks], acc[(qa)*2 + i][qb], 0, 0, 0);          \
    __builtin_amdgcn_s_setprio(0);

#define BAR()  __builtin_amdgcn_s_barrier(); __builtin_amdgcn_sched_barrier(0)
#define WAIT4() asm volatile("s_waitcnt vmcnt(4)" ::: "memory"); __builtin_amdgcn_sched_barrier(0)
#define WAIT0() asm volatile("s_waitcnt vmcnt(0)" ::: "memory"); __builtin_amdgcn_sched_barrier(0)

    STA(0, 0); STB(0, 0); STA(0, 1); STB(0, 1);
    STA(1, 0); STB(1, 0);

    const int NIT = K / 128;
    for (int it = 0; it < NIT - 1; ++it) {
        const int V = 2 * it + 1, W = 2 * it + 2, X2 = 2 * it + 3;
        WAIT4(); BAR();
        STA(V, 1); LDA(0, 0); LDB(0, 0, 0); MMQ(0, 0, 0);
        BAR();
        STB(V, 1); LDB(1, 0, 1); MMQ(0, 1, 1);
        BAR();
        STA(W, 0); LDA(1, 0); MMQ(1, 0, 0);
        BAR();
        STB(W, 0); MMQ(1, 1, 1);
        WAIT4(); BAR();
        STA(W, 1); LDA(0, 1); LDB(0, 1, 0); MMQ(0, 0, 0);
        BAR();
        STB(W, 1); LDB(1, 1, 1); MMQ(0, 1, 1);
        BAR();
        STA(X2, 0); LDA(1, 1); MMQ(1, 0, 0);
        BAR();
        STB(X2, 0); MMQ(1, 1, 1);
    }
    {
        const int V = 2 * NIT - 1;
        WAIT4(); BAR();
        STA(V, 1); LDA(0, 0); LDB(0, 0, 0); MMQ(0, 0, 0);
        BAR();
        STB(V, 1); LDB(1, 0, 1); MMQ(0, 1, 1);
        BAR();
        LDA(1, 0); MMQ(1, 0, 0);
        BAR();
        MMQ(1, 1, 1);
        WAIT0(); BAR();
        LDA(0, 1); LDB(0, 1, 0); MMQ(0, 0, 0);
        BAR();
        LDB(1, 1, 1); MMQ(0, 1, 1);
        BAR();
        LDA(1, 1); MMQ(1, 0, 0);
        BAR();
        MMQ(1, 1, 1);
    }
#undef MMQ
#undef BAR
#undef WAIT4
#undef WAIT0

#pragma unroll
    for (int fa = 0; fa < 4; fa++)
#pragma unroll
        for (int fb = 0; fb < 2; fb++) {
            int col = n0 + wn * 64 + fb * 32 + l31;
#pragma unroll
            for (int r = 0; r < 16; r++) {
                int rowg = m0 + wm * 128 + fa * 32 + (r & 3) + 8 * (r >> 2) + 4 * l5;
                C[(size_t)rowg * Dz + col] = acc[fa][fb][r] + Src[(size_t)rowg * Dz + col];
            }
        }
}

// ---------------- exact logit mirror for G: fill skipped lower-triangle tiles ----------------
__global__ __launch_bounds__(256) void mirror_g(
    short* __restrict__ F, int o0, long PS)
{
    __shared__ short ts[128][136];
    int p = blockIdx.x, b = blockIdx.y;
    int mi = 1, base = 0;
    while (p >= base + mi) { base += mi; mi++; }
    int nt = p - base;
    short* Fb = F + (size_t)b * PS;
    int t = threadIdx.x;
    int rr = t >> 1, c0 = (t & 1) * 64;
    const short* src = Fb + (size_t)(nt * 128 + rr) * Sz + o0 + mi * 128 + c0;
#pragma unroll
    for (int j = 0; j < 8; j++)
        *(short8v*)&ts[rr][c0 + j * 8] = *(const short8v*)(src + j * 8);
    __syncthreads();
    short* dst = Fb + (size_t)(mi * 128 + rr) * Sz + o0 + nt * 128 + c0;
#pragma unroll
    for (int j = 0; j < 8; j++) {
        short8v v;
#pragma unroll
        for (int e = 0; e < 8; e++) v[e] = ts[c0 + j * 8 + e][rr];
        *(short8v*)(dst + j * 8) = v;
    }
}

// ---------------- in-place batch softmax on fp16 logits (+ fused slab write) ----------------
__global__ __launch_bounds__(256) void softmax_ip(
    short* __restrict__ Qg, short* __restrict__ Qa,
    short* __restrict__ slab, int writeSlab, int nElem, long ps)
{
    int i8 = (blockIdx.x * 256 + threadIdx.x) * 8;
    if (i8 >= nElem) return;
    int z = blockIdx.z;
    short* Q = z ? Qa : Qg;

    short8v v[Bz];
    float f[Bz][8];
#pragma unroll
    for (int b = 0; b < Bz; b++) {
        v[b] = *(const short8v*)(Q + i8 + (size_t)b * ps);
#pragma unroll
        for (int e = 0; e < 8; e++) f[b][e] = h2f(v[b][e]);
    }
#pragma unroll
    for (int e = 0; e < 8; e++) {
        float mx = f[0][e];
#pragma unroll
        for (int b = 1; b < Bz; b++) mx = fmaxf(mx, f[b][e]);
        float sum = 0.f;
#pragma unroll
        for (int b = 0; b < Bz; b++) { f[b][e] = __expf(f[b][e] - mx); sum += f[b][e]; }
        float inv = 1.f / sum;
#pragma unroll
        for (int b = 0; b < Bz; b++) v[b][e] = f2h(f[b][e] * inv);
    }
#pragma unroll
    for (int b = 0; b < Bz; b++)
        *(short8v*)(Q + i8 + (size_t)b * ps) = v[b];

    int row = i8 >> 11;
    if (writeSlab && row >= 1020 && row < 1024) {
        int col = i8 & 2047;
        int roff = z * 65536 + (row - 1020) * 2048 + col;
#pragma unroll
        for (int b = 0; b < Bz; b++)
            *(short8v*)(slab + roff + b * 8192) = v[b];
    }
}

// ---------------- moca 5x5 conv over fp16 probs {G, A} (+slab rows) -> fp16 M ----------------
__global__ __launch_bounds__(256) void moca_kernel(
    const short* __restrict__ Gs, const short* __restrict__ As,
    const short* __restrict__ slab,
    const float* __restrict__ w3, const float* __restrict__ b3,
    short* __restrict__ Mout,
    int o0, int rlo, int slabLo, long psIn, long psOut)
{
    __shared__ float w[50];
    __shared__ float bb;
    int tid = threadIdx.x;
    if (tid < 50) w[tid] = w3[tid];
    if (tid == 50) bb = b3[0];
    __syncthreads();

    int t8 = tid * 8;
    int so = blockIdx.y, b = blockIdx.z;
    int s = o0 + so;
    const short* Gp = Gs + (size_t)b * psIn;
    const short* Ap = As + (size_t)b * psIn;

    float acc[8];
#pragma unroll
    for (int q = 0; q < 8; q++) acc[q] = bb;

#pragma unroll
    for (int i = 0; i < 5; i++) {
        int sr = s + i - 2;
        if (sr < 0 || sr >= Sz) continue;
        const short *gp, *ap;
        size_t ro;
        if (sr >= rlo) { gp = Gp; ap = Ap; ro = (size_t)(sr - rlo) * Sz; }
        else {
            gp = slab + (size_t)b * 8192;
            ap = slab + 65536 + (size_t)b * 8192;
            ro = (size_t)(sr - slabLo) * Sz;
        }
        float gw[16], aw[16];
#pragma unroll
        for (int g = 0; g < 4; g++) {
            int c0 = t8 - 4 + g * 4;
            if (c0 >= 0 && c0 + 3 < Sz) {
                short4v gv = *(const short4v*)(gp + ro + c0);
                short4v av = *(const short4v*)(ap + ro + c0);
#pragma unroll
                for (int e = 0; e < 4; e++) { gw[g * 4 + e] = h2f(gv[e]); aw[g * 4 + e] = h2f(av[e]); }
            } else {
#pragma unroll
                for (int e = 0; e < 4; e++) { gw[g * 4 + e] = 0.f; aw[g * 4 + e] = 0.f; }
            }
        }
#pragma unroll
        for (int j = 0; j < 5; j++) {
            float wg = w[i * 5 + j], wa = w[25 + i * 5 + j];
#pragma unroll
            for (int q = 0; q < 8; q++)
                acc[q] = fmaf(wg, gw[q + j + 2], fmaf(wa, aw[q + j + 2], acc[q]));
        }
    }
    short4v r0, r1;
#pragma unroll
    for (int q = 0; q < 4; q++) { r0[q] = f2h(acc[q]); r1[q] = f2h(acc[q + 4]); }
    short* op = Mout + (size_t)b * psOut + (size_t)so * Sz + t8;
    *(short4v*)op = r0;
    *(short4v*)(op + 4) = r1;
}

// ---------------- host ----------------
extern "C" void kernel_launch(void* const* d_in, const int* in_sizes, int n_in,
                              void* d_out, int out_size, void* d_ws, size_t ws_size,
                              hipStream_t stream)
{
    const float* x  = (const float*)d_in[0];
    const float* w1 = (const float*)d_in[1];
    const float* b1 = (const float*)d_in[2];
    const float* w2 = (const float*)d_in[3];
    const float* b2 = (const float*)d_in[4];
    const float* w3 = (const float*)d_in[5];
    const float* b3 = (const float*)d_in[6];
    const float* w4 = (const float*)d_in[7];
    const float* b4 = (const float*)d_in[8];
    float* out = (float*)d_out;

    const size_t SD = (size_t)Sz * Dz;
    const size_t BSD2 = (size_t)Bz * SD * 2;

    char* ws = (char*)d_ws;
    short* x16 = (short*)(ws);
    short* C1f = (short*)(ws + 1 * BSD2);
    short* C2f = (short*)(ws + 2 * BSD2);
    short* C4T = (short*)(ws + 3 * BSD2);
    char* strip0 = ws + 4 * BSD2;

    const size_t PS   = (size_t)1024 * Sz;
    const size_t PSM0 = (size_t)1022 * Sz;
    const size_t PSM1 = (size_t)1026 * Sz;
    short* Fg   = (short*)strip0;
    short* Fa   = Fg + (size_t)Bz * PS;
    short* Mf0  = Fa + (size_t)Bz * PS;
    short* slab = Mf0 + (size_t)Bz * PSM0;
    short* Mf1  = x16;

    conv3_kernel<<<dim3(1, Sz, Bz), 256, 0, stream>>>(
        x, w1, b1, w2, b2, x16, C1f, C2f);
    convT_kernel<<<dim3(Sz / 64, Dz / 64, Bz), 256, 0, stream>>>(x, w4, b4, C4T);

    const int ne = 1024 * Sz;

    // ---- strip 0: logit rows 0..1023 ----
    logit8_f16<<<dim3(8, 4, 16), 512, 0, stream>>>(
        x16, x16, C1f, C2f, Fg, Fa, 0, 0, (long)PS);
    mirror_g<<<dim3(28, Bz), 256, 0, stream>>>(Fg, 0, (long)PS);
    softmax_ip<<<dim3((ne / 8 + 255) / 256, 1, 2), 256, 0, stream>>>(
        Fg, Fa, slab, 1, ne, (long)PS);
    moca_kernel<<<dim3(1, 1022, Bz), 256, 0, stream>>>(
        Fg, Fa, slab, w3, b3, Mf0, 0, 0, 0, (long)PS, (long)PSM0);

    // ---- strip 1: logit rows 1024..2047 ----
    logit8_f16<<<dim3(8, 4, 16), 512, 0, stream>>>(
        x16 + (size_t)1024 * Dz, x16, C1f + (size_t)1024 * Dz, C2f,
        Fg, Fa, 1024, 4, (long)PS);
    mirror_g<<<dim3(28, Bz), 256, 0, stream>>>(Fg, 1024, (long)PS);
    softmax_ip<<<dim3((ne / 8 + 255) / 256, 1, 2), 256, 0, stream>>>(
        Fg, Fa, slab, 0, ne, (long)PS);
    moca_kernel<<<dim3(1, 1026, Bz), 256, 0, stream>>>(
        Fg, Fa, slab, w3, b3, Mf1, 1022, 1024, 1020, (long)PS, (long)PSM1);

    // ---- Wz = M @ C4T^T + x over ALL 2048 rows, one 8-phase dispatch ----
    wz8_f16<<<dim3(4, 8, 8), 512, 0, stream>>>(
        Mf0, Mf1, C4T, x, out, (long)PSM0, (long)PSM1);
}

// Round 20
// 505.543 us; speedup vs baseline: 1.0456x; 1.0456x over previous
//
// MoCA fused pipeline — round 20: exact revert to round-16 (506us measured best).
// 8-phase 256^2 16x16x32 logit GEMM (tri-skip+mirror, fp16 logits, G-diag offset),
// in-place batch softmax, slab+moca on probs, single full-matrix 8-phase wz8,
// r13 conv3, fused convT. This is the locked-in final composition.
#include <hip/hip_runtime.h>

#define Bz 8
#define Sz 2048
#define Dz 1024

typedef __attribute__((ext_vector_type(8))) _Float16 f16x8;
typedef __attribute__((ext_vector_type(8))) short short8v;
typedef __attribute__((ext_vector_type(4))) short short4v;
typedef __attribute__((ext_vector_type(4))) float f32x4;

__device__ __forceinline__ short f2h(float f) {
    _Float16 h = (_Float16)f;
    return __builtin_bit_cast(short, h);
}
__device__ __forceinline__ float h2f(short s) {
    return (float)__builtin_bit_cast(_Float16, s);
}
__device__ __forceinline__ void gld16(const void* g, void* l) {
    __builtin_amdgcn_global_load_lds(
        (const __attribute__((address_space(1))) void*)g,
        (__attribute__((address_space(3))) void*)l, 16, 0, 0);
}

// ---------------- fused 5x5 convs over x — 1 row/block (round-13 proven) ----------------
__global__ __launch_bounds__(256) void conv3_kernel(
    const float* __restrict__ x,
    const float* __restrict__ w1, const float* __restrict__ b1,
    const float* __restrict__ w2, const float* __restrict__ b2,
    short* __restrict__ x16, short* __restrict__ C1f, short* __restrict__ C2f)
{
    __shared__ float w[50];
    __shared__ float bias[2];
    const size_t SD = (size_t)Sz * Dz;
    int tid = threadIdx.x;
    if (tid < 25) w[tid] = w1[tid];
    else if (tid < 50) w[tid] = w2[tid - 25];
    if (tid == 50) { bias[0] = b1[0]; bias[1] = b2[0]; }
    __syncthreads();

    int d4 = tid * 4;
    int y = blockIdx.y;
    int s = ((y & 7) << 8) | (y >> 3);         // XCD-chunked row mapping
    int b = blockIdx.z;
    const float* xb = x + (size_t)b * SD + d4;

    float wv[5][12];
#pragma unroll
    for (int i = 0; i < 5; i++) {
        int ss = s + i - 2;
        int ssc = ss < 0 ? 0 : (ss >= Sz ? Sz - 1 : ss);
        const float* rp = xb + (size_t)ssc * Dz;
        if (d4 > 0) *(float4*)&wv[i][0] = *(const float4*)(rp - 4);
        else { wv[i][0] = wv[i][1] = wv[i][2] = wv[i][3] = 0.f; }
        *(float4*)&wv[i][4] = *(const float4*)rp;
        if (d4 < 1020) *(float4*)&wv[i][8] = *(const float4*)(rp + 4);
        else { wv[i][8] = wv[i][9] = wv[i][10] = wv[i][11] = 0.f; }
        if (ss != ssc) {
#pragma unroll
            for (int q = 0; q < 12; q++) wv[i][q] = 0.f;
        }
    }

    float o1[4] = {}, o2[4] = {};
#pragma unroll
    for (int i = 0; i < 5; i++)
#pragma unroll
        for (int j = 0; j < 5; j++) {
            float c1w = w[i * 5 + j], c2w = w[25 + j * 5 + i];
#pragma unroll
            for (int q = 0; q < 4; q++) {
                float v = wv[i][q + j + 2];
                o1[q] = fmaf(c1w, v, o1[q]);
                o2[q] = fmaf(c2w, v, o2[q]);
            }
        }
    size_t o = (size_t)b * SD + (size_t)s * Dz + d4;
    short4v hx, h1, h2;
#pragma unroll
    for (int q = 0; q < 4; q++) {
        hx[q] = f2h(wv[2][q + 4]);
        h1[q] = f2h(o1[q] + bias[0]);
        h2[q] = f2h(o2[q] + bias[1]);
    }
    *(short4v*)(x16 + o) = hx;
    *(short4v*)(C1f + o) = h1;
    *(short4v*)(C2f + o) = h2;
}

// ---------------- fused conv_g (5x5) + transpose: x[s,d] -> C4T[d,s] fp16 ----------------
__global__ __launch_bounds__(256) void convT_kernel(
    const float* __restrict__ x, const float* __restrict__ w4,
    const float* __restrict__ b4, short* __restrict__ C4T)
{
    __shared__ float xs[68][73];
    __shared__ short ct[64][72];
    __shared__ float w[25];
    __shared__ float bb;
    const size_t SD = (size_t)Sz * Dz;
    int tid = threadIdx.x;
    if (tid < 25) w[tid] = w4[tid];
    if (tid == 25) bb = b4[0];

    int s0 = blockIdx.x * 64, d0 = blockIdx.y * 64, b = blockIdx.z;
    const float* xb = x + (size_t)b * SD;
    for (int k = tid; k < 68 * 68; k += 256) {
        int r = k / 68, c = k - r * 68;
        int gr = s0 - 2 + r, gc = d0 - 2 + c;
        float v = 0.f;
        if (gr >= 0 && gr < Sz && gc >= 0 && gc < Dz) v = xb[(size_t)gr * Dz + gc];
        xs[r][c] = v;
    }
    __syncthreads();

    int sl = tid & 63, dg = tid >> 6;
    float acc[16];
#pragma unroll
    for (int q = 0; q < 16; q++) acc[q] = bb;
#pragma unroll
    for (int i = 0; i < 5; i++) {
        float row[20];
#pragma unroll
        for (int m = 0; m < 20; m++) row[m] = xs[sl + i][dg * 16 + m];
#pragma unroll
        for (int j = 0; j < 5; j++) {
            float wv = w[i * 5 + j];
#pragma unroll
            for (int q = 0; q < 16; q++) acc[q] = fmaf(wv, row[q + j], acc[q]);
        }
    }
#pragma unroll
    for (int q = 0; q < 16; q++) ct[dg * 16 + q][sl] = f2h(acc[q]);
    __syncthreads();

    int dl = tid >> 2, sc = (tid & 3) * 16;
    f16x8 v0 = *(const f16x8*)&ct[dl][sc];
    f16x8 v1 = *(const f16x8*)&ct[dl][sc + 8];
    short* op = C4T + (size_t)b * SD + (size_t)(d0 + dl) * Sz + s0 + sc;
    *(f16x8*)op = v0;
    *(f16x8*)(op + 8) = v1;
}

// ---------------- 8-phase 256x256 logit GEMM, fp16 out (round-13 verified) ----------------
__global__ __launch_bounds__(512, 2) void logit8_f16(
    const short* __restrict__ Ag, const short* __restrict__ Bg,
    const short* __restrict__ Aa, const short* __restrict__ Ba,
    short* __restrict__ Qg, short* __restrict__ Qa,
    int rlo, int sq256off, long PS)
{
    __shared__ char lds[131072];

    int flat = blockIdx.x + 8 * (blockIdx.y + 4 * blockIdx.z);
    int nid = (flat & 7) * 64 + (flat >> 3);
    int bx = nid & 7, by = (nid >> 3) & 3, bz = nid >> 5;
    const int map = bz >> 3, bzb = bz & 7;
    if (map == 0) {
        int ntl = bx - sq256off;
        if (ntl >= 0 && ntl < 4 && ntl < by) return;
    }

    const size_t SD = (size_t)Sz * Dz;
    const int K = Dz;
    const short* A = (map ? Aa : Ag) + (size_t)bzb * SD;
    const short* B = (map ? Ba : Bg) + (size_t)bzb * SD;
    short* Q = (map ? Qa : Qg) + (size_t)bzb * PS;

    const int m0 = by * 256, n0 = bx * 256;
    const int t = threadIdx.x;
    const int lane = t & 63;
    const int w = t >> 6;
    const int wm = w >> 2, wn = w & 3;
    const int fr = lane & 15;
    const int kb = lane >> 4;

    const int cc16 = ((t & 7) ^ ((t >> 3) & 7)) * 16;
    const int tr = t >> 3;
    const int bdst = (t >> 8) * 8192 + ((t >> 3) & 31) * 128 + (t & 7) * 16;

    auto STA = [&](int tile, int h) {
        char* base = lds + (tile & 1) * 65536;
#pragma unroll
        for (int j = 0; j < 2; j++) {
            int row = m0 + j * 128 + h * 64 + tr;
            gld16((const char*)A + ((size_t)row * K + tile * 64) * 2 + cc16,
                  base + j * 16384 + h * 8192 + t * 16);
        }
    };
    auto STB = [&](int tile, int h) {
        char* base = lds + (tile & 1) * 65536 + 32768;
#pragma unroll
        for (int j = 0; j < 2; j++) {
            int u = j * 64 + tr;
            int row = n0 + (u >> 5) * 64 + h * 32 + (u & 31);
            gld16((const char*)B + ((size_t)row * K + tile * 64) * 2 + cc16,
                  base + j * 16384 + h * 4096 + bdst);
        }
    };

    int aoff[2], boff[2];
#pragma unroll
    for (int ks = 0; ks < 2; ks++) {
        int slot = ((ks * 4 + kb) ^ (fr & 7)) * 16;
        aoff[ks] = (wm * 128 + fr) * 128 + slot;
        boff[ks] = (wn * 64 + fr) * 128 + slot;
    }

    f16x8 aR[8];
    f16x8 bR[2][4];
    f32x4 acc[8][4];
#pragma unroll
    for (int i = 0; i < 8; i++)
#pragma unroll
        for (int j = 0; j < 4; j++) acc[i][j] = (f32x4){0.f, 0.f, 0.f, 0.f};

    auto LDA = [&](int qa, int d) {
        const char* p = lds + d * 65536 + qa * 8192;
#pragma unroll
        for (int f = 0; f < 4; f++)
#pragma unroll
            for (int ks = 0; ks < 2; ks++)
                aR[f * 2 + ks] = *(const f16x8*)(p + aoff[ks] + f * 2048);
    };
    auto LDB = [&](int qb, int d, int which) {
        const char* p = lds + d * 65536 + 32768 + qb * 4096;
#pragma unroll
        for (int g = 0; g < 2; g++)
#pragma unroll
            for (int ks = 0; ks < 2; ks++)
                bR[which][g * 2 + ks] = *(const f16x8*)(p + boff[ks] + g * 2048);
    };
#define MMQ(qa, qb, which)                                                        \
    __builtin_amdgcn_s_setprio(1);                                                \
    _Pragma("unroll") for (int f = 0; f < 4; f++)                                 \
        _Pragma("unroll") for (int g = 0; g < 2; g++)                             \
            _Pragma("unroll") for (int ks = 0; ks < 2; ks++)                      \
                acc[(qa)*4 + f][(qb)*2 + g] = __builtin_amdgcn_mfma_f32_16x16x32_f16( \
                    aR[f * 2 + ks], bR[which][g * 2 + ks], acc[(qa)*4 + f][(qb)*2 + g], 0, 0, 0); \
    __builtin_amdgcn_s_setprio(0);

#define BAR()  __builtin_amdgcn_s_barrier(); __builtin_amdgcn_sched_barrier(0)
#define WAIT4() asm volatile("s_waitcnt vmcnt(4)" ::: "memory"); __builtin_amdgcn_sched_barrier(0)
#define WAIT0() asm volatile("s_waitcnt vmcnt(0)" ::: "memory"); __builtin_amdgcn_sched_barrier(0)

    STA(0, 0); STB(0, 0); STA(0, 1); STB(0, 1);
    STA(1, 0); STB(1, 0);

    const int NIT = K / 128;
    for (int it = 0; it < NIT - 1; ++it) {
        const int V = 2 * it + 1, W = 2 * it + 2, X = 2 * it + 3;
        WAIT4(); BAR();
        STA(V, 1); LDA(0, 0); LDB(0, 0, 0); MMQ(0, 0, 0);
        BAR();
        STB(V, 1); LDB(1, 0, 1); MMQ(0, 1, 1);
        BAR();
        STA(W, 0); LDA(1, 0); MMQ(1, 0, 0);
        BAR();
        STB(W, 0); MMQ(1, 1, 1);
        WAIT4(); BAR();
        STA(W, 1); LDA(0, 1); LDB(0, 1, 0); MMQ(0, 0, 0);
        BAR();
        STB(W, 1); LDB(1, 1, 1); MMQ(0, 1, 1);
        BAR();
        STA(X, 0); LDA(1, 1); MMQ(1, 0, 0);
        BAR();
        STB(X, 0); MMQ(1, 1, 1);
    }
    {
        const int V = 2 * NIT - 1;
        WAIT4(); BAR();
        STA(V, 1); LDA(0, 0); LDB(0, 0, 0); MMQ(0, 0, 0);
        BAR();
        STB(V, 1); LDB(1, 0, 1); MMQ(0, 1, 1);
        BAR();
        LDA(1, 0); MMQ(1, 0, 0);
        BAR();
        MMQ(1, 1, 1);
        WAIT0(); BAR();
        LDA(0, 1); LDB(0, 1, 0); MMQ(0, 0, 0);
        BAR();
        LDB(1, 1, 1); MMQ(0, 1, 1);
        BAR();
        LDA(1, 1); MMQ(1, 0, 0);
        BAR();
        MMQ(1, 1, 1);
    }
#undef MMQ
#undef BAR
#undef WAIT4
#undef WAIT0

#pragma unroll
    for (int mf = 0; mf < 8; mf++)
#pragma unroll
        for (int nf = 0; nf < 4; nf++) {
            int col = n0 + wn * 64 + nf * 16 + fr;
#pragma unroll
            for (int r = 0; r < 4; r++) {
                int rowg = m0 + wm * 128 + mf * 16 + kb * 4 + r;
                float o = acc[mf][nf][r];
                if (map == 0 && rlo + rowg == col) o -= 1024.f;
                Q[(size_t)rowg * Sz + col] = f2h(o);
            }
        }
}

// ---------------- 8-phase 256x256 Wz GEMM: M=2048 full, fp32 out + x ----------------
__global__ __launch_bounds__(512, 2) void wz8_f16(
    const short* __restrict__ M0, const short* __restrict__ M1,
    const short* __restrict__ C4Tm,
    const float* __restrict__ X, float* __restrict__ Out,
    long psM0, long psM1)
{
    __shared__ char lds[131072];

    int flat = blockIdx.x + 4 * (blockIdx.y + 8 * blockIdx.z);
    int nid = (flat & 7) * 32 + (flat >> 3);
    int bx = nid & 3, by = (nid >> 2) & 7, bz = nid >> 5;

    const size_t SD = (size_t)Sz * Dz;
    const int K = Sz;
    const short* A0 = M0 + (size_t)bz * psM0;
    const short* A1 = M1 + (size_t)bz * psM1;
    const short* B = C4Tm + (size_t)bz * SD;
    const float* Src = X + (size_t)bz * SD;
    float* C = Out + (size_t)bz * SD;

    const int m0 = by * 256, n0 = bx * 256;
    const int t = threadIdx.x;
    const int lane = t & 63;
    const int w = t >> 6;
    const int wm = w >> 2, wn = w & 3;
    const int fr = lane & 15;
    const int kb = lane >> 4;

    const int cc16 = ((t & 7) ^ ((t >> 3) & 7)) * 16;
    const int tr = t >> 3;
    const int bdst = (t >> 8) * 8192 + ((t >> 3) & 31) * 128 + (t & 7) * 16;

    auto STA = [&](int tile, int h) {
        char* base = lds + (tile & 1) * 65536;
#pragma unroll
        for (int j = 0; j < 2; j++) {
            int row = m0 + j * 128 + h * 64 + tr;
            const short* src = (row < 1022) ? (A0 + (size_t)row * K)
                                            : (A1 + (size_t)(row - 1022) * K);
            gld16((const char*)src + (size_t)tile * 128 + cc16,
                  base + j * 16384 + h * 8192 + t * 16);
        }
    };
    auto STB = [&](int tile, int h) {
        char* base = lds + (tile & 1) * 65536 + 32768;
#pragma unroll
        for (int j = 0; j < 2; j++) {
            int u = j * 64 + tr;
            int row = n0 + (u >> 5) * 64 + h * 32 + (u & 31);
            gld16((const char*)B + ((size_t)row * K + tile * 64) * 2 + cc16,
                  base + j * 16384 + h * 4096 + bdst);
        }
    };

    int aoff[2], boff[2];
#pragma unroll
    for (int ks = 0; ks < 2; ks++) {
        int slot = ((ks * 4 + kb) ^ (fr & 7)) * 16;
        aoff[ks] = (wm * 128 + fr) * 128 + slot;
        boff[ks] = (wn * 64 + fr) * 128 + slot;
    }

    f16x8 aR[8];
    f16x8 bR[2][4];
    f32x4 acc[8][4];
#pragma unroll
    for (int i = 0; i < 8; i++)
#pragma unroll
        for (int j = 0; j < 4; j++) acc[i][j] = (f32x4){0.f, 0.f, 0.f, 0.f};

    auto LDA = [&](int qa, int d) {
        const char* p = lds + d * 65536 + qa * 8192;
#pragma unroll
        for (int f = 0; f < 4; f++)
#pragma unroll
            for (int ks = 0; ks < 2; ks++)
                aR[f * 2 + ks] = *(const f16x8*)(p + aoff[ks] + f * 2048);
    };
    auto LDB = [&](int qb, int d, int which) {
        const char* p = lds + d * 65536 + 32768 + qb * 4096;
#pragma unroll
        for (int g = 0; g < 2; g++)
#pragma unroll
            for (int ks = 0; ks < 2; ks++)
                bR[which][g * 2 + ks] = *(const f16x8*)(p + boff[ks] + g * 2048);
    };
#define MMQ(qa, qb, which)                                                        \
    __builtin_amdgcn_s_setprio(1);                                                \
    _Pragma("unroll") for (int f = 0; f < 4; f++)                                 \
        _Pragma("unroll") for (int g = 0; g < 2; g++)                             \
            _Pragma("unroll") for (int ks = 0; ks < 2; ks++)                      \
                acc[(qa)*4 + f][(qb)*2 + g] = __builtin_amdgcn_mfma_f32_16x16x32_f16( \
                    aR[f * 2 + ks], bR[which][g * 2 + ks], acc[(qa)*4 + f][(qb)*2 + g], 0, 0, 0); \
    __builtin_amdgcn_s_setprio(0);

#define BAR()  __builtin_amdgcn_s_barrier(); __builtin_amdgcn_sched_barrier(0)
#define WAIT4() asm volatile("s_waitcnt vmcnt(4)" ::: "memory"); __builtin_amdgcn_sched_barrier(0)
#define WAIT0() asm volatile("s_waitcnt vmcnt(0)" ::: "memory"); __builtin_amdgcn_sched_barrier(0)

    STA(0, 0); STB(0, 0); STA(0, 1); STB(0, 1);
    STA(1, 0); STB(1, 0);

    const int NIT = K / 128;
    for (int it = 0; it < NIT - 1; ++it) {
        const int V = 2 * it + 1, W = 2 * it + 2, X2 = 2 * it + 3;
        WAIT4(); BAR();
        STA(V, 1); LDA(0, 0); LDB(0, 0, 0); MMQ(0, 0, 0);
        BAR();
        STB(V, 1); LDB(1, 0, 1); MMQ(0, 1, 1);
        BAR();
        STA(W, 0); LDA(1, 0); MMQ(1, 0, 0);
        BAR();
        STB(W, 0); MMQ(1, 1, 1);
        WAIT4(); BAR();
        STA(W, 1); LDA(0, 1); LDB(0, 1, 0); MMQ(0, 0, 0);
        BAR();
        STB(W, 1); LDB(1, 1, 1); MMQ(0, 1, 1);
        BAR();
        STA(X2, 0); LDA(1, 1); MMQ(1, 0, 0);
        BAR();
        STB(X2, 0); MMQ(1, 1, 1);
    }
    {
        const int V = 2 * NIT - 1;
        WAIT4(); BAR();
        STA(V, 1); LDA(0, 0); LDB(0, 0, 0); MMQ(0, 0, 0);
        BAR();
        STB(V, 1); LDB(1, 0, 1); MMQ(0, 1, 1);
        BAR();
        LDA(1, 0); MMQ(1, 0, 0);
        BAR();
        MMQ(1, 1, 1);
        WAIT0(); BAR();
        LDA(0, 1); LDB(0, 1, 0); MMQ(0, 0, 0);
        BAR();
        LDB(1, 1, 1); MMQ(0, 1, 1);
        BAR();
        LDA(1, 1); MMQ(1, 0, 0);
        BAR();
        MMQ(1, 1, 1);
    }
#undef MMQ
#undef BAR
#undef WAIT4
#undef WAIT0

#pragma unroll
    for (int mf = 0; mf < 8; mf++)
#pragma unroll
        for (int nf = 0; nf < 4; nf++) {
            int col = n0 + wn * 64 + nf * 16 + fr;
#pragma unroll
            for (int r = 0; r < 4; r++) {
                int rowg = m0 + wm * 128 + mf * 16 + kb * 4 + r;
                C[(size_t)rowg * Dz + col] = acc[mf][nf][r] + Src[(size_t)rowg * Dz + col];
            }
        }
}

// ---------------- exact logit mirror for G: fill skipped lower-triangle tiles ----------------
__global__ __launch_bounds__(256) void mirror_g(
    short* __restrict__ F, int o0, long PS)
{
    __shared__ short ts[128][136];
    int p = blockIdx.x, b = blockIdx.y;
    int mi = 1, base = 0;
    while (p >= base + mi) { base += mi; mi++; }
    int nt = p - base;
    short* Fb = F + (size_t)b * PS;
    int t = threadIdx.x;
    int rr = t >> 1, c0 = (t & 1) * 64;
    const short* src = Fb + (size_t)(nt * 128 + rr) * Sz + o0 + mi * 128 + c0;
#pragma unroll
    for (int j = 0; j < 8; j++)
        *(short8v*)&ts[rr][c0 + j * 8] = *(const short8v*)(src + j * 8);
    __syncthreads();
    short* dst = Fb + (size_t)(mi * 128 + rr) * Sz + o0 + nt * 128 + c0;
#pragma unroll
    for (int j = 0; j < 8; j++) {
        short8v v;
#pragma unroll
        for (int e = 0; e < 8; e++) v[e] = ts[c0 + j * 8 + e][rr];
        *(short8v*)(dst + j * 8) = v;
    }
}

// ---------------- in-place batch softmax on fp16 logits (both maps) ----------------
__global__ __launch_bounds__(256) void softmax_ip(
    short* __restrict__ Qg, short* __restrict__ Qa, int nElem, long ps)
{
    int i8 = (blockIdx.x * 256 + threadIdx.x) * 8;
    if (i8 >= nElem) return;
    short* Q = blockIdx.z ? Qa : Qg;

    short8v v[Bz];
    float f[Bz][8];
#pragma unroll
    for (int b = 0; b < Bz; b++) {
        v[b] = *(const short8v*)(Q + i8 + (size_t)b * ps);
#pragma unroll
        for (int e = 0; e < 8; e++) f[b][e] = h2f(v[b][e]);
    }
#pragma unroll
    for (int e = 0; e < 8; e++) {
        float mx = f[0][e];
#pragma unroll
        for (int b = 1; b < Bz; b++) mx = fmaxf(mx, f[b][e]);
        float sum = 0.f;
#pragma unroll
        for (int b = 0; b < Bz; b++) { f[b][e] = __expf(f[b][e] - mx); sum += f[b][e]; }
        float inv = 1.f / sum;
#pragma unroll
        for (int b = 0; b < Bz; b++) v[b][e] = f2h(f[b][e] * inv);
    }
#pragma unroll
    for (int b = 0; b < Bz; b++)
        *(short8v*)(Q + i8 + (size_t)b * ps) = v[b];
}

// ---------------- slab copy: save prob rows 1020..1023 (both maps) ----------------
__global__ __launch_bounds__(256) void slab_copy(
    const short* __restrict__ Fg, const short* __restrict__ Fa,
    short* __restrict__ slab, long PS)
{
    int idx = blockIdx.x * 256 + threadIdx.x;
    int e = idx * 8;
    int map = e >> 16;
    int rem = e & 65535;
    int b = rem >> 13;
    int rem2 = rem & 8191;
    int row = rem2 >> 11;
    int col = rem2 & 2047;
    const short* src = (map ? Fa : Fg) + (size_t)b * PS + (size_t)(1020 + row) * Sz + col;
    *(short8v*)(slab + e) = *(const short8v*)src;
}

// ---------------- moca 5x5 conv over fp16 probs {G, A} (+slab rows) -> fp16 M ----------------
__global__ __launch_bounds__(256) void moca_kernel(
    const short* __restrict__ Gs, const short* __restrict__ As,
    const short* __restrict__ slab,
    const float* __restrict__ w3, const float* __restrict__ b3,
    short* __restrict__ Mout,
    int o0, int rlo, int slabLo, long psIn, long psOut)
{
    __shared__ float w[50];
    __shared__ float bb;
    int tid = threadIdx.x;
    if (tid < 50) w[tid] = w3[tid];
    if (tid == 50) bb = b3[0];
    __syncthreads();

    int t8 = tid * 8;
    int so = blockIdx.y, b = blockIdx.z;
    int s = o0 + so;
    const short* Gp = Gs + (size_t)b * psIn;
    const short* Ap = As + (size_t)b * psIn;

    float acc[8];
#pragma unroll
    for (int q = 0; q < 8; q++) acc[q] = bb;

#pragma unroll
    for (int i = 0; i < 5; i++) {
        int sr = s + i - 2;
        if (sr < 0 || sr >= Sz) continue;
        const short *gp, *ap;
        size_t ro;
        if (sr >= rlo) { gp = Gp; ap = Ap; ro = (size_t)(sr - rlo) * Sz; }
        else {
            gp = slab + (size_t)b * 8192;
            ap = slab + 65536 + (size_t)b * 8192;
            ro = (size_t)(sr - slabLo) * Sz;
        }
        float gw[16], aw[16];
#pragma unroll
        for (int g = 0; g < 4; g++) {
            int c0 = t8 - 4 + g * 4;
            if (c0 >= 0 && c0 + 3 < Sz) {
                short4v gv = *(const short4v*)(gp + ro + c0);
                short4v av = *(const short4v*)(ap + ro + c0);
#pragma unroll
                for (int e = 0; e < 4; e++) { gw[g * 4 + e] = h2f(gv[e]); aw[g * 4 + e] = h2f(av[e]); }
            } else {
#pragma unroll
                for (int e = 0; e < 4; e++) { gw[g * 4 + e] = 0.f; aw[g * 4 + e] = 0.f; }
            }
        }
#pragma unroll
        for (int j = 0; j < 5; j++) {
            float wg = w[i * 5 + j], wa = w[25 + i * 5 + j];
#pragma unroll
            for (int q = 0; q < 8; q++)
                acc[q] = fmaf(wg, gw[q + j + 2], fmaf(wa, aw[q + j + 2], acc[q]));
        }
    }
    short4v r0, r1;
#pragma unroll
    for (int q = 0; q < 4; q++) { r0[q] = f2h(acc[q]); r1[q] = f2h(acc[q + 4]); }
    short* op = Mout + (size_t)b * psOut + (size_t)so * Sz + t8;
    *(short4v*)op = r0;
    *(short4v*)(op + 4) = r1;
}

// ---------------- host ----------------
extern "C" void kernel_launch(void* const* d_in, const int* in_sizes, int n_in,
                              void* d_out, int out_size, void* d_ws, size_t ws_size,
                              hipStream_t stream)
{
    const float* x  = (const float*)d_in[0];
    const float* w1 = (const float*)d_in[1];
    const float* b1 = (const float*)d_in[2];
    const float* w2 = (const float*)d_in[3];
    const float* b2 = (const float*)d_in[4];
    const float* w3 = (const float*)d_in[5];
    const float* b3 = (const float*)d_in[6];
    const float* w4 = (const float*)d_in[7];
    const float* b4 = (const float*)d_in[8];
    float* out = (float*)d_out;

    const size_t SD = (size_t)Sz * Dz;
    const size_t BSD2 = (size_t)Bz * SD * 2;

    char* ws = (char*)d_ws;
    short* x16 = (short*)(ws);
    short* C1f = (short*)(ws + 1 * BSD2);
    short* C2f = (short*)(ws + 2 * BSD2);
    short* C4T = (short*)(ws + 3 * BSD2);
    char* strip0 = ws + 4 * BSD2;

    const size_t PS   = (size_t)1024 * Sz;
    const size_t PSM0 = (size_t)1022 * Sz;       // strip-0 M rows 0..1021
    const size_t PSM1 = (size_t)1026 * Sz;       // strip-1 M rows 1022..2047
    short* Fg   = (short*)strip0;
    short* Fa   = Fg + (size_t)Bz * PS;
    short* Mf0  = Fa + (size_t)Bz * PS;
    short* slab = Mf0 + (size_t)Bz * PSM0;       // [2][8][4][2048] probs = 256KB
    short* Mf1  = x16;                           // aliases dead x16/C1f after strip-1 logit

    conv3_kernel<<<dim3(1, Sz, Bz), 256, 0, stream>>>(
        x, w1, b1, w2, b2, x16, C1f, C2f);
    convT_kernel<<<dim3(Sz / 64, Dz / 64, Bz), 256, 0, stream>>>(x, w4, b4, C4T);

    const int ne = 1024 * Sz;

    // ---- strip 0: logit rows 0..1023 ----
    logit8_f16<<<dim3(8, 4, 16), 512, 0, stream>>>(
        x16, x16, C1f, C2f, Fg, Fa, 0, 0, (long)PS);
    mirror_g<<<dim3(28, Bz), 256, 0, stream>>>(Fg, 0, (long)PS);
    softmax_ip<<<dim3((ne / 8 + 255) / 256, 1, 2), 256, 0, stream>>>(Fg, Fa, ne, (long)PS);
    slab_copy<<<dim3(64), 256, 0, stream>>>(Fg, Fa, slab, (long)PS);
    moca_kernel<<<dim3(1, 1022, Bz), 256, 0, stream>>>(
        Fg, Fa, slab, w3, b3, Mf0, 0, 0, 0, (long)PS, (long)PSM0);

    // ---- strip 1: logit rows 1024..2047 ----
    logit8_f16<<<dim3(8, 4, 16), 512, 0, stream>>>(
        x16 + (size_t)1024 * Dz, x16, C1f + (size_t)1024 * Dz, C2f,
        Fg, Fa, 1024, 4, (long)PS);
    mirror_g<<<dim3(28, Bz), 256, 0, stream>>>(Fg, 1024, (long)PS);
    softmax_ip<<<dim3((ne / 8 + 255) / 256, 1, 2), 256, 0, stream>>>(Fg, Fa, ne, (long)PS);
    // strip-1 moca writes into the dead x16/C1f region
    moca_kernel<<<dim3(1, 1026, Bz), 256, 0, stream>>>(
        Fg, Fa, slab, w3, b3, Mf1, 1022, 1024, 1020, (long)PS, (long)PSM1);

    // ---- Wz = M @ C4T^T + x over ALL 2048 rows, one 8-phase dispatch ----
    wz8_f16<<<dim3(4, 8, 8), 512, 0, stream>>>(
        Mf0, Mf1, C4T, x, out, (long)PSM0, (long)PSM1);
}